// Round 1
// baseline (2518.368 us; speedup 1.0000x reference)
//
#include <hip/hip_runtime.h>

#define NB 4096
#define MAXN 25

// One block per batch: corner MLP -> pairing -> line MLP -> maxpool, all in LDS.
__global__ __launch_bounds__(256, 2) void batch_kernel(
    const float* __restrict__ fpoc,
    const float* __restrict__ cw1, const float* __restrict__ cb1,
    const float* __restrict__ cw2, const float* __restrict__ cb2,
    const float* __restrict__ lw1, const float* __restrict__ lb1,
    const float* __restrict__ lw2, const float* __restrict__ lb2,
    const int* __restrict__ nfpc,
    float* __restrict__ pooled)
{
    __shared__ float s_pair[MAXN * 256];   // 25.6 KB (h lives in first 128 cols)
    __shared__ float s_hid[MAXN * 512];    // 51.2 KB (also scratch for h1)
    __shared__ float s_x[MAXN * 2];
    __shared__ int s_n;

    const int b = blockIdx.x;
    const int tid = threadIdx.x;

    if (tid == 0) s_n = nfpc[b];
    if (tid < MAXN * 2) s_x[tid] = fpoc[b * (MAXN * 2) + tid];
    __syncthreads();
    const int n = s_n;

    // ---- corner layer 1: h1[25][64] = relu(x @ cw1 + cb1), in s_hid scratch
    float* s_h1 = s_hid;
    for (int e = tid; e < MAXN * 64; e += 256) {
        int i = e >> 6, j = e & 63;
        float v = s_x[i * 2] * cw1[j] + s_x[i * 2 + 1] * cw1[64 + j] + cb1[j];
        s_h1[e] = fmaxf(v, 0.0f);
    }
    __syncthreads();

    // ---- corner layer 2 (no relu): h[25][128] into pair[:, 0:128]
    for (int e = tid; e < MAXN * 128; e += 256) {
        int i = e >> 7, j = e & 127;
        float acc = cb2[j];
        const float* h1r = &s_h1[i * 64];
        #pragma unroll 8
        for (int k = 0; k < 64; ++k) acc += h1r[k] * cw2[k * 128 + j];
        s_pair[i * 256 + j] = acc;
    }
    __syncthreads();

    // ---- pairing: pair[i][128:256] = h[(i+1)%n]; zero invalid rows
    for (int e = tid; e < MAXN * 128; e += 256) {
        int i = e >> 7, j = e & 127;
        if (i < n) {
            int nx = i + 1; if (nx == n) nx = 0;
            s_pair[i * 256 + 128 + j] = s_pair[nx * 256 + j];
        } else {
            s_pair[i * 256 + j] = 0.0f;
            s_pair[i * 256 + 128 + j] = 0.0f;
        }
    }
    __syncthreads();

    // ---- line layer 1: hid[25][512] = relu(pair @ lw1 + lb1)
    // 5 groups of 5 rows; each thread does 2 output channels per group.
    for (int g = 0; g < 5; ++g) {
        const float* pr = &s_pair[g * 5 * 256];
        for (int jt = 0; jt < 2; ++jt) {
            const int j = jt * 256 + tid;
            float a0 = 0.f, a1 = 0.f, a2 = 0.f, a3 = 0.f, a4 = 0.f;
            for (int k = 0; k < 256; ++k) {
                float w = lw1[k * 512 + j];
                a0 += pr[0 * 256 + k] * w;
                a1 += pr[1 * 256 + k] * w;
                a2 += pr[2 * 256 + k] * w;
                a3 += pr[3 * 256 + k] * w;
                a4 += pr[4 * 256 + k] * w;
            }
            const float bb = lb1[j];
            s_hid[(g * 5 + 0) * 512 + j] = fmaxf(a0 + bb, 0.0f);
            s_hid[(g * 5 + 1) * 512 + j] = fmaxf(a1 + bb, 0.0f);
            s_hid[(g * 5 + 2) * 512 + j] = fmaxf(a2 + bb, 0.0f);
            s_hid[(g * 5 + 3) * 512 + j] = fmaxf(a3 + bb, 0.0f);
            s_hid[(g * 5 + 4) * 512 + j] = fmaxf(a4 + bb, 0.0f);
        }
    }
    __syncthreads();

    // ---- line layer 2 (no relu) + masked maxpool.
    // All 25 rows register-blocked against each lw2 load (lw2 read once per block).
    for (int p = 0; p < 2; ++p) {
        float acc0[MAXN], acc1[MAXN];
        #pragma unroll
        for (int r = 0; r < MAXN; ++r) { acc0[r] = 0.f; acc1[r] = 0.f; }
        const int j0 = p * 512 + tid;
        const int j1 = j0 + 256;
        for (int k = 0; k < 512; ++k) {
            float w0 = lw2[k * 1024 + j0];
            float w1 = lw2[k * 1024 + j1];
            #pragma unroll
            for (int r = 0; r < MAXN; ++r) {
                float hv = s_hid[r * 512 + k];   // wave-uniform -> LDS broadcast
                acc0[r] += hv * w0;
                acc1[r] += hv * w1;
            }
        }
        float m0 = -3.4e38f, m1 = -3.4e38f;
        #pragma unroll
        for (int r = 0; r < MAXN; ++r) {
            if (r < n) { m0 = fmaxf(m0, acc0[r]); m1 = fmaxf(m1, acc1[r]); }
        }
        pooled[b * 1024 + j0] = m0 + lb2[j0];
        pooled[b * 1024 + j1] = m1 + lb2[j1];
    }
}

// pooled[4096,1024] @ fw[1024,511] + fb -> out[4096,511]
__global__ __launch_bounds__(256, 2) void final_kernel(
    const float* __restrict__ pooled, const float* __restrict__ fw,
    const float* __restrict__ fb, float* __restrict__ out)
{
    __shared__ float s_p[16 * 1024];   // 64 KB
    const int rb = blockIdx.x * 16;
    const int tid = threadIdx.x;
    for (int e = tid; e < 16 * 1024; e += 256) s_p[e] = pooled[rb * 1024 + e];
    __syncthreads();

    const int j0 = tid;           // always < 511
    const int j1 = tid + 256;     // valid iff < 511
    const bool v1 = (j1 < 511);

    float acc0[16], acc1[16];
    #pragma unroll
    for (int r = 0; r < 16; ++r) { acc0[r] = 0.f; acc1[r] = 0.f; }

    for (int k = 0; k < 1024; ++k) {
        float w0 = fw[k * 511 + j0];
        float w1 = v1 ? fw[k * 511 + j1] : 0.0f;
        #pragma unroll
        for (int r = 0; r < 16; ++r) {
            float pv = s_p[r * 1024 + k];   // wave-uniform -> LDS broadcast
            acc0[r] += pv * w0;
            acc1[r] += pv * w1;
        }
    }
    const float b0 = fb[j0];
    const float b1 = v1 ? fb[j1] : 0.0f;
    #pragma unroll
    for (int r = 0; r < 16; ++r) {
        out[(rb + r) * 511 + j0] = acc0[r] + b0;
        if (v1) out[(rb + r) * 511 + j1] = acc1[r] + b1;
    }
}

extern "C" void kernel_launch(void* const* d_in, const int* in_sizes, int n_in,
                              void* d_out, int out_size, void* d_ws, size_t ws_size,
                              hipStream_t stream)
{
    const float* fpoc = (const float*)d_in[0];
    const float* cw1  = (const float*)d_in[1];
    const float* cb1  = (const float*)d_in[2];
    const float* cw2  = (const float*)d_in[3];
    const float* cb2  = (const float*)d_in[4];
    const float* lw1  = (const float*)d_in[5];
    const float* lb1  = (const float*)d_in[6];
    const float* lw2  = (const float*)d_in[7];
    const float* lb2  = (const float*)d_in[8];
    const float* fw   = (const float*)d_in[9];
    const float* fb   = (const float*)d_in[10];
    const int*  nfpc  = (const int*)d_in[11];

    float* pooled = (float*)d_ws;              // 4096*1024 fp32 = 16.8 MB
    float* out = (float*)d_out;

    hipLaunchKernelGGL(batch_kernel, dim3(NB), dim3(256), 0, stream,
                       fpoc, cw1, cb1, cw2, cb2, lw1, lb1, lw2, lb2, nfpc, pooled);
    hipLaunchKernelGGL(final_kernel, dim3(NB / 16), dim3(256), 0, stream,
                       pooled, fw, fb, out);
}

// Round 2
// 437.812 us; speedup vs baseline: 5.7522x; 5.7522x over previous
//
#include <hip/hip_runtime.h>

typedef __attribute__((ext_vector_type(8))) short bf16x8;
typedef __attribute__((ext_vector_type(4))) float f32x4;

#define MFMA16(a, b, c) __builtin_amdgcn_mfma_f32_16x16x32_bf16((a), (b), (c), 0, 0, 0)

__device__ __forceinline__ unsigned short f2bf(float x) {
    union { float f; unsigned u; } v; v.f = x;
    unsigned r = v.u + 0x7fffu + ((v.u >> 16) & 1u);
    return (unsigned short)(r >> 16);
}

// ---------------- weight prep: fp32 -> bf16, transposed to [N][K] ----------------
__global__ void convert_kernel(
    const float* __restrict__ lw1, const float* __restrict__ lw2, const float* __restrict__ fw,
    short* __restrict__ lw1t, short* __restrict__ lw2t, short* __restrict__ fwt)
{
    int t = blockIdx.x * 256 + threadIdx.x;
    if (t < 131072) {                       // lw1t[512][256] <- lw1[256][512]
        int n = t >> 8, k = t & 255;
        lw1t[t] = (short)f2bf(lw1[k * 512 + n]);
    } else if (t < 131072 + 524288) {       // lw2t[1024][512] <- lw2[512][1024]
        int u = t - 131072;
        int n = u >> 9, k = u & 511;
        lw2t[u] = (short)f2bf(lw2[k * 1024 + n]);
    } else if (t < 131072 + 524288 + 524288) { // fwt[512][1024] <- fw[1024][511], row 511 = 0
        int v = t - 655360;
        int n = v >> 10, k = v & 1023;
        fwt[v] = (n < 511) ? (short)f2bf(fw[k * 511 + n]) : (short)0;
    }
}

// ---------------- fused: corner MLP + pairing + line MLP (MFMA) + maxpool ----------------
// 3 batches per block, M = 80 rows (75 real + 5 pad), 512 threads = 8 waves.
#define NBATCH 3
#define SP_HID   0              // bf16 [80][512]  (81920 B)  -- also corner scratch
#define H1_OFF   0              // f32 [75][64]    (19200 B)
#define H_OFF    19200          // f32 [75][128]   (38400 B)
#define CW2_OFF  57600          // f32 [64][128]   (32768 B)  (tail overlaps SP_PAIR; dead before pairing)
#define SP_PAIR  81920          // bf16 [80][256]  (40960 B)
#define SX_OFF   122880         // f32 [80][2]
#define SN_OFF   123520         // int [4]
#define SMEM_SZ  123536

__global__ __launch_bounds__(512, 2) void fused_kernel(
    const float* __restrict__ fpoc,
    const float* __restrict__ cw1, const float* __restrict__ cb1,
    const float* __restrict__ cw2, const float* __restrict__ cb2,
    const short* __restrict__ lw1t,   // bf16 [512][256]
    const float* __restrict__ lb1,
    const short* __restrict__ lw2t,   // bf16 [1024][512]
    const float* __restrict__ lb2,
    const int* __restrict__ nfpc,
    unsigned short* __restrict__ pooled_b)  // bf16 [4096][1024]
{
    __shared__ __align__(16) char smem[SMEM_SZ];

    const int blk = blockIdx.x;
    const int b0 = blk * NBATCH;
    const int nb = min(NBATCH, 4096 - b0);
    const int tid = threadIdx.x;
    const int w = tid >> 6, l = tid & 63, q = l >> 4, ln = l & 15;

    float* s_x  = (float*)(smem + SX_OFF);
    float* s_h1 = (float*)(smem + H1_OFF);
    float* s_h  = (float*)(smem + H_OFF);
    float* s_cw2 = (float*)(smem + CW2_OFF);
    int* s_n = (int*)(smem + SN_OFF);

    // stage cw2 (64x128 f32), x, n
    for (int e = tid; e < 64 * 128; e += 512) s_cw2[e] = cw2[e];
    for (int e = tid; e < nb * 50; e += 512) s_x[e] = fpoc[b0 * 50 + e];
    if (tid < 3) s_n[tid] = (tid < nb) ? nfpc[b0 + tid] : 0;
    __syncthreads();
    const int n0 = s_n[0], n1 = s_n[1], n2 = s_n[2];

    // corner layer 1: h1 = relu(x @ cw1 + cb1)   [nb*25][64] f32
    for (int e = tid; e < nb * 25 * 64; e += 512) {
        int i = e >> 6, j = e & 63;
        float v = s_x[i * 2] * cw1[j] + s_x[i * 2 + 1] * cw1[64 + j] + cb1[j];
        s_h1[e] = fmaxf(v, 0.f);
    }
    __syncthreads();

    // corner layer 2 (no relu): h = h1 @ cw2 + cb2   [nb*25][128] f32
    for (int e = tid; e < nb * 25 * 128; e += 512) {
        int i = e >> 7, j = e & 127;
        float a = cb2[j];
        const float* h1r = &s_h1[i * 64];
        #pragma unroll
        for (int k = 0; k < 64; ++k) a += h1r[k] * s_cw2[k * 128 + j];
        s_h[i * 128 + j] = a;
    }
    __syncthreads();

    // pairing -> s_pair bf16 [80][256], XOR-swizzled; zeros for invalid/pad rows
    for (int e = tid; e < 80 * 256; e += 512) {
        int i = e >> 8, c = e & 255;
        float val = 0.f;
        if (i < nb * 25) {
            int g = i / 25;
            int li = i - g * 25;
            int ng = (g == 0) ? n0 : ((g == 1) ? n1 : n2);
            if (li < ng) {
                if (c < 128) val = s_h[i * 128 + c];
                else {
                    int li2 = li + 1; if (li2 == ng) li2 = 0;
                    val = s_h[(g * 25 + li2) * 128 + (c - 128)];
                }
            }
        }
        int off = (i * 512 + c * 2) ^ ((i & 7) << 4);
        *(unsigned short*)(smem + SP_PAIR + off) = f2bf(val);
    }
    __syncthreads();

    // ---- line layer 1 (MFMA): hid = relu(pair @ lw1 + lb1) -> s_hid bf16 [80][512]
    {
        const int nbase = w * 64;   // each wave owns 64 cols
        f32x4 acc[5][4];
        #pragma unroll
        for (int m = 0; m < 5; ++m)
            #pragma unroll
            for (int j = 0; j < 4; ++j) acc[m][j] = 0;
        #pragma unroll 2
        for (int ks = 0; ks < 8; ++ks) {       // K = 256
            bf16x8 a[5], bfr[4];
            #pragma unroll
            for (int m = 0; m < 5; ++m) {
                int row = 16 * m + ln;
                int off = (row * 512 + ks * 64 + q * 16) ^ ((row & 7) << 4);
                a[m] = *(const bf16x8*)(smem + SP_PAIR + off);
            }
            #pragma unroll
            for (int j = 0; j < 4; ++j) {
                int col = nbase + j * 16 + ln;
                bfr[j] = *(const bf16x8*)(lw1t + col * 256 + ks * 32 + q * 8);
            }
            #pragma unroll
            for (int m = 0; m < 5; ++m)
                #pragma unroll
                for (int j = 0; j < 4; ++j)
                    acc[m][j] = MFMA16(a[m], bfr[j], acc[m][j]);
        }
        // epilogue: relu+bias -> s_hid (disjoint from s_pair; no barrier needed before)
        #pragma unroll
        for (int j = 0; j < 4; ++j) {
            int col = nbase + j * 16 + ln;
            float bias = lb1[col];
            #pragma unroll
            for (int m = 0; m < 5; ++m) {
                #pragma unroll
                for (int r = 0; r < 4; ++r) {
                    int row = 16 * m + q * 4 + r;
                    float v = fmaxf(acc[m][j][r] + bias, 0.f);
                    int off = (row * 1024 + col * 2) ^ ((row & 7) << 4);
                    *(unsigned short*)(smem + SP_HID + off) = f2bf(v);
                }
            }
        }
    }
    __syncthreads();

    // ---- line layer 2 (MFMA) + masked maxpool -> pooled_b bf16
    #pragma unroll 1
    for (int c = 0; c < 2; ++c) {
        const int nbase = w * 128 + c * 64;    // wave owns 128 cols in 2 chunks of 64
        f32x4 acc[5][4];
        #pragma unroll
        for (int m = 0; m < 5; ++m)
            #pragma unroll
            for (int j = 0; j < 4; ++j) acc[m][j] = 0;
        #pragma unroll 2
        for (int ks = 0; ks < 16; ++ks) {      // K = 512
            bf16x8 a[5], bfr[4];
            #pragma unroll
            for (int m = 0; m < 5; ++m) {
                int row = 16 * m + ln;
                int off = (row * 1024 + ks * 64 + q * 16) ^ ((row & 7) << 4);
                a[m] = *(const bf16x8*)(smem + SP_HID + off);
            }
            #pragma unroll
            for (int j = 0; j < 4; ++j) {
                int col = nbase + j * 16 + ln;
                bfr[j] = *(const bf16x8*)(lw2t + col * 512 + ks * 32 + q * 8);
            }
            #pragma unroll
            for (int m = 0; m < 5; ++m)
                #pragma unroll
                for (int j = 0; j < 4; ++j)
                    acc[m][j] = MFMA16(a[m], bfr[j], acc[m][j]);
        }
        // masked max over rows of each batch, reduced across lane-q groups
        auto tilemax = [&](const f32x4& v4, int m, int g, int ng) -> float {
            float v = -3.4e38f;
            #pragma unroll
            for (int r = 0; r < 4; ++r) {
                int row = 16 * m + q * 4 + r;
                bool ok = (row >= 25 * g) && (row < 25 * g + ng);
                v = ok ? fmaxf(v, v4[r]) : v;
            }
            v = fmaxf(v, __shfl_xor(v, 16));
            v = fmaxf(v, __shfl_xor(v, 32));
            return v;
        };
        #pragma unroll
        for (int j = 0; j < 4; ++j) {
            float m0 = tilemax(acc[0][j], 0, 0, n0);
            m0 = fmaxf(m0, tilemax(acc[1][j], 1, 0, n0));
            float m1 = tilemax(acc[1][j], 1, 1, n1);
            m1 = fmaxf(m1, tilemax(acc[2][j], 2, 1, n1));
            m1 = fmaxf(m1, tilemax(acc[3][j], 3, 1, n1));
            float m2 = tilemax(acc[3][j], 3, 2, n2);
            m2 = fmaxf(m2, tilemax(acc[4][j], 4, 2, n2));
            if (l < 16) {
                int col = nbase + j * 16 + l;
                float bias = lb2[col];
                if (0 < nb) pooled_b[(b0 + 0) * 1024 + col] = f2bf(m0 + bias);
                if (1 < nb) pooled_b[(b0 + 1) * 1024 + col] = f2bf(m1 + bias);
                if (2 < nb) pooled_b[(b0 + 2) * 1024 + col] = f2bf(m2 + bias);
            }
        }
    }
}

// ---------------- final: pooled[4096,1024] @ fw[1024,511] + fb ----------------
// BM=128 (8 waves x 16 rows), BN=64, grid (32, 8)
__global__ __launch_bounds__(512, 2) void final_kernel(
    const unsigned short* __restrict__ pooled_b,
    const short* __restrict__ fwt,    // bf16 [512][1024]
    const float* __restrict__ fb,
    float* __restrict__ out)
{
    const int tid = threadIdx.x;
    const int w = tid >> 6, l = tid & 63, q = l >> 4, ln = l & 15;
    const int rb = blockIdx.x * 128 + w * 16;
    const int nb0 = blockIdx.y * 64;

    f32x4 acc[4];
    #pragma unroll
    for (int j = 0; j < 4; ++j) acc[j] = 0;

    const short* pb = (const short*)pooled_b;
    #pragma unroll 4
    for (int ks = 0; ks < 32; ++ks) {          // K = 1024
        bf16x8 a = *(const bf16x8*)(pb + (rb + ln) * 1024 + ks * 32 + q * 8);
        #pragma unroll
        for (int j = 0; j < 4; ++j) {
            bf16x8 bf = *(const bf16x8*)(fwt + (nb0 + j * 16 + ln) * 1024 + ks * 32 + q * 8);
            acc[j] = MFMA16(a, bf, acc[j]);
        }
    }
    #pragma unroll
    for (int j = 0; j < 4; ++j) {
        int col = nb0 + j * 16 + ln;
        if (col < 511) {
            float bias = fb[col];
            #pragma unroll
            for (int r = 0; r < 4; ++r) {
                int row = rb + q * 4 + r;
                out[row * 511 + col] = acc[j][r] + bias;
            }
        }
    }
}

extern "C" void kernel_launch(void* const* d_in, const int* in_sizes, int n_in,
                              void* d_out, int out_size, void* d_ws, size_t ws_size,
                              hipStream_t stream)
{
    const float* fpoc = (const float*)d_in[0];
    const float* cw1  = (const float*)d_in[1];
    const float* cb1  = (const float*)d_in[2];
    const float* cw2  = (const float*)d_in[3];
    const float* cb2  = (const float*)d_in[4];
    const float* lw1  = (const float*)d_in[5];
    const float* lb1  = (const float*)d_in[6];
    const float* lw2  = (const float*)d_in[7];
    const float* lb2  = (const float*)d_in[8];
    const float* fw   = (const float*)d_in[9];
    const float* fb   = (const float*)d_in[10];
    const int*  nfpc  = (const int*)d_in[11];

    char* ws = (char*)d_ws;
    unsigned short* pooled_b = (unsigned short*)(ws);            // 8,388,608 B
    short* lw1t = (short*)(ws + 8388608);                        //   262,144 B
    short* lw2t = (short*)(ws + 8388608 + 262144);               // 1,048,576 B
    short* fwt  = (short*)(ws + 8388608 + 262144 + 1048576);     // 1,048,576 B

    hipLaunchKernelGGL(convert_kernel, dim3(4608), dim3(256), 0, stream,
                       lw1, lw2, fw, lw1t, lw2t, fwt);

    hipLaunchKernelGGL(fused_kernel, dim3((4096 + NBATCH - 1) / NBATCH), dim3(512), 0, stream,
                       fpoc, cw1, cb1, cw2, cb2, lw1t, lb1, lw2t, lb2, nfpc, pooled_b);

    hipLaunchKernelGGL(final_kernel, dim3(32, 8), dim3(512), 0, stream,
                       pooled_b, fwt, fb, (float*)d_out);
}

// Round 3
// 282.720 us; speedup vs baseline: 8.9076x; 1.5486x over previous
//
#include <hip/hip_runtime.h>

typedef __attribute__((ext_vector_type(8))) short bf16x8;
typedef __attribute__((ext_vector_type(4))) float f32x4;

#define MFMA16(a, b, c) __builtin_amdgcn_mfma_f32_16x16x32_bf16((a), (b), (c), 0, 0, 0)

static __device__ __forceinline__ unsigned short f2bf(float x) {
    union { float f; unsigned u; } v; v.f = x;
    unsigned r = v.u + 0x7fffu + ((v.u >> 16) & 1u);
    return (unsigned short)(r >> 16);
}

// async global->LDS, 16B per lane. LDS dest = lane0 base + lane*16.
static __device__ __forceinline__ void gload16(const void* g, void* l) {
    __builtin_amdgcn_global_load_lds(
        (const __attribute__((address_space(1))) unsigned int*)g,
        (__attribute__((address_space(3))) unsigned int*)l, 16, 0, 0);
}

// ---------------- weight prep: fp32 -> bf16, transposed to [N][K] ----------------
__global__ void convert_kernel(
    const float* __restrict__ lw1, const float* __restrict__ lw2, const float* __restrict__ fw,
    short* __restrict__ lw1t, short* __restrict__ lw2t, short* __restrict__ fwt)
{
    int t = blockIdx.x * 256 + threadIdx.x;
    if (t < 131072) {                       // lw1t[512][256] <- lw1[256][512]
        int n = t >> 8, k = t & 255;
        lw1t[t] = (short)f2bf(lw1[k * 512 + n]);
    } else if (t < 131072 + 524288) {       // lw2t[1024][512] <- lw2[512][1024]
        int u = t - 131072;
        int n = u >> 9, k = u & 511;
        lw2t[u] = (short)f2bf(lw2[k * 1024 + n]);
    } else if (t < 131072 + 524288 + 524288) { // fwt[512][1024] <- fw[1024][511], row 511 = 0
        int v = t - 655360;
        int n = v >> 10, k = v & 1023;
        fwt[v] = (n < 511) ? (short)f2bf(fw[k * 511 + n]) : (short)0;
    }
}

// ---------------- corner MLP: fpoc -> h_b bf16 [4096][32][128] (rows 25..31 zero) ----
#define CB 4
__global__ __launch_bounds__(256, 2) void corner_kernel(
    const float* __restrict__ fpoc,
    const float* __restrict__ cw1, const float* __restrict__ cb1,
    const float* __restrict__ cw2, const float* __restrict__ cb2,
    unsigned short* __restrict__ h_b)
{
    __shared__ float s_h1[CB * 25 * 64];   // 25.6 KB
    __shared__ float s_cw2[64 * 128];      // 32 KB
    __shared__ float s_x[CB * 25 * 2];
    const int b0 = blockIdx.x * CB;
    const int t = threadIdx.x;

    for (int e = t; e < 64 * 128; e += 256) s_cw2[e] = cw2[e];
    for (int e = t; e < CB * 50; e += 256) s_x[e] = fpoc[b0 * 50 + e];
    __syncthreads();

    for (int e = t; e < CB * 25 * 64; e += 256) {
        int i = e >> 6, j = e & 63;
        float v = s_x[i * 2] * cw1[j] + s_x[i * 2 + 1] * cw1[64 + j] + cb1[j];
        s_h1[e] = fmaxf(v, 0.f);
    }
    __syncthreads();

    for (int e = t; e < CB * 25 * 128; e += 256) {
        int i = e >> 7, j = e & 127;
        float a = cb2[j];
        const float* h1r = &s_h1[i * 64];
        #pragma unroll
        for (int k = 0; k < 64; ++k) a += h1r[k] * s_cw2[k * 128 + j];
        int b = b0 + i / 25, ii = i % 25;
        h_b[(b * 32 + ii) * 128 + j] = f2bf(a);
    }
    for (int e = t; e < CB * 7 * 128; e += 256) {
        int i = e >> 7, j = e & 127;
        int b = b0 + i / 7, ii = 25 + i % 7;
        h_b[(b * 32 + ii) * 128 + j] = 0;
    }
}

// ---------------- gemm1: pair(gathered from h_b) @ lw1t^T -> relu+lb1 -> hid ----------
// m97 structure: 128x128 tile, BK=64, 4 waves (2x2), global_load_lds w=16, XOR swizzle.
__global__ __launch_bounds__(256, 2) void gemm1_kernel(
    const unsigned short* __restrict__ h_b,   // [4096][32][128]
    const short* __restrict__ lw1t,           // [512][256]
    const float* __restrict__ lb1,
    const int* __restrict__ nfpc,
    unsigned short* __restrict__ hid,         // [crows][512] chunk-local
    int row0, int pm)
{
    __shared__ __align__(16) char ldsA[16384];
    __shared__ __align__(16) char ldsB[16384];
    __shared__ int s_n[4];

    const int nwg = pm * 4;
    int bid = blockIdx.x;
    int bid2 = (bid & 7) * (nwg >> 3) + (bid >> 3);   // XCD swizzle (nwg%8==0)
    const int pr = bid2 >> 2, pc = bid2 & 3;
    const int t = threadIdx.x;
    const int w = t >> 6, l = t & 63, q = l >> 4, ln = l & 15;
    const int wr = w >> 1, wc = w & 1;
    const int R = row0 + pr * 128;                    // global padded-row base

    if (t < 4) s_n[t] = nfpc[(R >> 5) + t];
    __syncthreads();

    f32x4 acc[4][4];
    #pragma unroll
    for (int m = 0; m < 4; ++m)
        #pragma unroll
        for (int n = 0; n < 4; ++n) acc[m][n] = 0;

    for (int kt = 0; kt < 4; ++kt) {
        const int k0 = kt * 64;
        // ---- stage A: gather pair rows from h_b (pre-swizzled source)
        #pragma unroll
        for (int i = 0; i < 4; ++i) {
            int o = i * 4096 + t * 16;
            int row = o >> 7, colb = o & 127;
            int colb2 = colb ^ ((row & 7) << 4);
            int k = k0 + (colb2 >> 1);                // 0..255
            int g = R + row;
            int ii = g & 31;
            int n = s_n[row >> 5];
            int srow, kk2;
            if (k < 128) { srow = ii; kk2 = k; }
            else { srow = (ii < n) ? ((ii + 1 == n) ? 0 : ii + 1) : 0; kk2 = k - 128; }
            const unsigned short* src = h_b + ((unsigned)((g >> 5) * 32 + srow)) * 128 + kk2;
            gload16(src, ldsA + o);
        }
        // ---- stage B from lw1t
        #pragma unroll
        for (int i = 0; i < 4; ++i) {
            int o = i * 4096 + t * 16;
            int row = o >> 7, colb = o & 127;
            int colb2 = colb ^ ((row & 7) << 4);
            const short* src = lw1t + (pc * 128 + row) * 256 + k0 + (colb2 >> 1);
            gload16(src, ldsB + o);
        }
        asm volatile("s_waitcnt vmcnt(0)");
        __syncthreads();
        #pragma unroll
        for (int kk = 0; kk < 2; ++kk) {
            bf16x8 af[4], bf[4];
            #pragma unroll
            for (int m = 0; m < 4; ++m) {
                int row = wr * 64 + m * 16 + ln;
                int off = (row * 128 + kk * 64 + q * 16) ^ ((row & 7) << 4);
                af[m] = *(const bf16x8*)(ldsA + off);
            }
            #pragma unroll
            for (int n = 0; n < 4; ++n) {
                int row = wc * 64 + n * 16 + ln;
                int off = (row * 128 + kk * 64 + q * 16) ^ ((row & 7) << 4);
                bf[n] = *(const bf16x8*)(ldsB + off);
            }
            #pragma unroll
            for (int m = 0; m < 4; ++m)
                #pragma unroll
                for (int n = 0; n < 4; ++n)
                    acc[m][n] = MFMA16(af[m], bf[n], acc[m][n]);
        }
        __syncthreads();
    }
    // ---- epilogue: relu + bias -> hid bf16
    #pragma unroll
    for (int n = 0; n < 4; ++n) {
        int col = pc * 128 + wc * 64 + n * 16 + ln;
        float bias = lb1[col];
        #pragma unroll
        for (int m = 0; m < 4; ++m) {
            int lrow = pr * 128 + wr * 64 + m * 16 + q * 4;
            #pragma unroll
            for (int r = 0; r < 4; ++r)
                hid[(size_t)(lrow + r) * 512 + col] = f2bf(fmaxf(acc[m][n][r] + bias, 0.f));
        }
    }
}

// ---------------- gemm2: hid @ lw2t^T (+lb2) + masked maxpool -> pooled bf16 ----------
__global__ __launch_bounds__(256, 2) void gemm2_kernel(
    const unsigned short* __restrict__ hid,   // [crows][512]
    const short* __restrict__ lw2t,           // [1024][512]
    const float* __restrict__ lb2,
    const int* __restrict__ nfpc,
    unsigned short* __restrict__ pooled_b,    // [4096][1024]
    int row0, int pm)
{
    __shared__ __align__(16) char ldsA[16384];
    __shared__ __align__(16) char ldsB[16384];
    __shared__ int s_n[4];

    const int nwg = pm * 8;
    int bid = blockIdx.x;
    int bid2 = (bid & 7) * (nwg >> 3) + (bid >> 3);
    const int pr = bid2 >> 3, pc = bid2 & 7;
    const int t = threadIdx.x;
    const int w = t >> 6, l = t & 63, q = l >> 4, ln = l & 15;
    const int wr = w >> 1, wc = w & 1;
    const int Rl = pr * 128;                       // chunk-local row base
    const int bg0 = (row0 + Rl) >> 5;              // global batch base

    if (t < 4) s_n[t] = nfpc[bg0 + t];
    __syncthreads();

    f32x4 acc[4][4];
    #pragma unroll
    for (int m = 0; m < 4; ++m)
        #pragma unroll
        for (int n = 0; n < 4; ++n) acc[m][n] = 0;

    for (int kt = 0; kt < 8; ++kt) {
        const int k0 = kt * 64;
        #pragma unroll
        for (int i = 0; i < 4; ++i) {
            int o = i * 4096 + t * 16;
            int row = o >> 7, colb = o & 127;
            int colb2 = colb ^ ((row & 7) << 4);
            const unsigned short* src = hid + (size_t)(Rl + row) * 512 + k0 + (colb2 >> 1);
            gload16(src, ldsA + o);
        }
        #pragma unroll
        for (int i = 0; i < 4; ++i) {
            int o = i * 4096 + t * 16;
            int row = o >> 7, colb = o & 127;
            int colb2 = colb ^ ((row & 7) << 4);
            const short* src = lw2t + (pc * 128 + row) * 512 + k0 + (colb2 >> 1);
            gload16(src, ldsB + o);
        }
        asm volatile("s_waitcnt vmcnt(0)");
        __syncthreads();
        #pragma unroll
        for (int kk = 0; kk < 2; ++kk) {
            bf16x8 af[4], bf[4];
            #pragma unroll
            for (int m = 0; m < 4; ++m) {
                int row = wr * 64 + m * 16 + ln;
                int off = (row * 128 + kk * 64 + q * 16) ^ ((row & 7) << 4);
                af[m] = *(const bf16x8*)(ldsA + off);
            }
            #pragma unroll
            for (int n = 0; n < 4; ++n) {
                int row = wc * 64 + n * 16 + ln;
                int off = (row * 128 + kk * 64 + q * 16) ^ ((row & 7) << 4);
                bf[n] = *(const bf16x8*)(ldsB + off);
            }
            #pragma unroll
            for (int m = 0; m < 4; ++m)
                #pragma unroll
                for (int n = 0; n < 4; ++n)
                    acc[m][n] = MFMA16(af[m], bf[n], acc[m][n]);
        }
        __syncthreads();
    }

    // ---- masked maxpool epilogue (batch = 32 rows = m-tile pairs within this wave)
    #pragma unroll
    for (int n = 0; n < 4; ++n) {
        int col = pc * 128 + wc * 64 + n * 16 + ln;
        float v0 = -3.4e38f, v1 = -3.4e38f;
        #pragma unroll
        for (int m = 0; m < 4; ++m) {
            int nb = s_n[wr * 2 + (m >> 1)];
            #pragma unroll
            for (int r = 0; r < 4; ++r) {
                int rowb = (m & 1) * 16 + q * 4 + r;
                bool ok = rowb < nb;
                float x = acc[m][n][r];
                if (m < 2) v0 = ok ? fmaxf(v0, x) : v0;
                else       v1 = ok ? fmaxf(v1, x) : v1;
            }
        }
        v0 = fmaxf(v0, __shfl_xor(v0, 16)); v0 = fmaxf(v0, __shfl_xor(v0, 32));
        v1 = fmaxf(v1, __shfl_xor(v1, 16)); v1 = fmaxf(v1, __shfl_xor(v1, 32));
        if (l < 16) {
            float bias = lb2[col];
            pooled_b[(size_t)(bg0 + wr * 2 + 0) * 1024 + col] = f2bf(v0 + bias);
            pooled_b[(size_t)(bg0 + wr * 2 + 1) * 1024 + col] = f2bf(v1 + bias);
        }
    }
}

// ---------------- final: pooled[4096,1024] @ fw[1024,511] + fb ----------------
__global__ __launch_bounds__(512, 2) void final_kernel(
    const unsigned short* __restrict__ pooled_b,
    const short* __restrict__ fwt,    // bf16 [512][1024]
    const float* __restrict__ fb,
    float* __restrict__ out)
{
    const int tid = threadIdx.x;
    const int w = tid >> 6, l = tid & 63, q = l >> 4, ln = l & 15;
    const int rb = blockIdx.x * 128 + w * 16;
    const int nb0 = blockIdx.y * 64;

    f32x4 acc[4];
    #pragma unroll
    for (int j = 0; j < 4; ++j) acc[j] = 0;

    const short* pb = (const short*)pooled_b;
    #pragma unroll 4
    for (int ks = 0; ks < 32; ++ks) {
        bf16x8 a = *(const bf16x8*)(pb + (rb + ln) * 1024 + ks * 32 + q * 8);
        #pragma unroll
        for (int j = 0; j < 4; ++j) {
            bf16x8 bf = *(const bf16x8*)(fwt + (nb0 + j * 16 + ln) * 1024 + ks * 32 + q * 8);
            acc[j] = MFMA16(a, bf, acc[j]);
        }
    }
    #pragma unroll
    for (int j = 0; j < 4; ++j) {
        int col = nb0 + j * 16 + ln;
        if (col < 511) {
            float bias = fb[col];
            #pragma unroll
            for (int r = 0; r < 4; ++r) {
                int row = rb + q * 4 + r;
                out[row * 511 + col] = acc[j][r] + bias;
            }
        }
    }
}

extern "C" void kernel_launch(void* const* d_in, const int* in_sizes, int n_in,
                              void* d_out, int out_size, void* d_ws, size_t ws_size,
                              hipStream_t stream)
{
    const float* fpoc = (const float*)d_in[0];
    const float* cw1  = (const float*)d_in[1];
    const float* cb1  = (const float*)d_in[2];
    const float* cw2  = (const float*)d_in[3];
    const float* cb2  = (const float*)d_in[4];
    const float* lw1  = (const float*)d_in[5];
    const float* lb1  = (const float*)d_in[6];
    const float* lw2  = (const float*)d_in[7];
    const float* lb2  = (const float*)d_in[8];
    const float* fw   = (const float*)d_in[9];
    const float* fb   = (const float*)d_in[10];
    const int*  nfpc  = (const int*)d_in[11];

    char* ws = (char*)d_ws;
    unsigned short* pooled_b = (unsigned short*)(ws);            // 8,388,608
    short* lw1t = (short*)(ws + 8388608);                        //   262,144
    short* lw2t = (short*)(ws + 8650752);                        // 1,048,576
    short* fwt  = (short*)(ws + 9699328);                        // 1,048,576
    unsigned short* h_b = (unsigned short*)(ws + 10747904);      // 33,554,432
    const size_t hid_off = 44302336;
    unsigned short* hid = (unsigned short*)(ws + hid_off);

    // adaptive chunking of the 134 MB hid buffer
    size_t avail = (ws_size > hid_off) ? ws_size - hid_off : 0;
    int n_chunks = 1;
    while (n_chunks < 16 && (size_t)(134217728u / n_chunks) > avail) n_chunks <<= 1;
    const int crows = 131072 / n_chunks;
    const int pm = crows / 128;

    hipLaunchKernelGGL(convert_kernel, dim3(4608), dim3(256), 0, stream,
                       lw1, lw2, fw, lw1t, lw2t, fwt);
    hipLaunchKernelGGL(corner_kernel, dim3(1024), dim3(256), 0, stream,
                       fpoc, cw1, cb1, cw2, cb2, h_b);
    for (int c = 0; c < n_chunks; ++c) {
        int row0 = c * crows;
        hipLaunchKernelGGL(gemm1_kernel, dim3(pm * 4), dim3(256), 0, stream,
                           h_b, lw1t, lb1, nfpc, hid, row0, pm);
        hipLaunchKernelGGL(gemm2_kernel, dim3(pm * 8), dim3(256), 0, stream,
                           hid, lw2t, lb2, nfpc, pooled_b, row0, pm);
    }
    hipLaunchKernelGGL(final_kernel, dim3(32, 8), dim3(512), 0, stream,
                       pooled_b, fwt, fb, (float*)d_out);
}